// Round 3
// baseline (249.242 us; speedup 1.0000x reference)
//
#include <hip/hip_runtime.h>
#include <hip/hip_bf16.h>
#include <hip/hip_fp16.h>
#include <math.h>

// ---------------------------------------------------------------------------
// PointsToImage: ball-query (K=32, R=0.1) -> PointNetConv msg=[x_j, pos_j-pos_dst]
// -> Linear(66,128) -> masked-BatchNorm -> ReLU -> Linear(128,64) -> scatter-max
// into pixel nodes, output [B=32, F=64, 32, 32] fp32.
//
// R15: k_out 32x32 MFMA restructure (rocprof R14: k_out 51us, all pipes <33%,
// FETCH fixed at 9MB -> latency/issue-bound, not L2-miss-bound).
//  - k_out uses mfma_f32_32x32x16_f16: lane l IS edge row l&31, so the
//    nbrs-load feeds the gather address directly (no shfl hop); one gather
//    instruction covers all 32 edges (8 gathers/query instead of 16); A-build
//    pk-VALU halves; epilogue = 16 masked fmax + 1 shfl_xor(32) + coalesced
//    store at scratch[isq*64+lane].
//  - 1 query per wave (8192 blocks), all 8 wbuf + 8 shp loads hoisted before
//    the MFMA loop; s_setprio(1) around the MFMA cluster.
//  - k_bq prep packs a second W2 B-frag buffer (w2b32, 32x32 layout) at
//    WS_W2B32; k_self keeps the verified 16x16 path.
// Pipeline (6 launches): k_bq -> k_y -> k_finalize -> k_self -> k_out -> k_gather
// ---------------------------------------------------------------------------

#define NPTS   32768
#define KNB    32
#define BN_EPS 1e-5f

// workspace layout (bytes) -- same envelope as R11 (max 39,344,128)
#define WS_NBRS     0u           // int[NPTS*KNB]      = 4194304
#define WS_NBRCNT   4194304u     // int[NPTS]          = 131072
#define WS_W2B32    4325376u     // ushort[8192]       (W2 B-frag, fp16, 32x32 layout)
#define WS_SCSH     4719616u     // float[256]
#define WS_W2B      4720640u     // ushort[8192]       (W2 B-frag, fp16, 16x16 layout)
#define WS_PART     4737024u     // float[256*516]     = 528384
#define WS_Y        5265408u     // uint[NPTS*64]      = 8388608 (yb; dead after k_self)
#define WS_SCRATCH  5265408u     // float[NPTS*64]     (OVERLAYS yb)
#define WS_WB       13654016u    // uint[NPTS*64]      = 8388608 (w, fp16 pairs)
#define WS_QCNT     22042624u    // int[NPTS]
#define WS_QSTART   22173696u    // int[NPTS]
#define WS_QLIST    22304768u    // int[NPTS]
#define WS_ISLOT    22435840u    // int[NPTS]
#define WS_SELF     22566912u    // float[NPTS*64]     = 8388608
#define WS_SHP      30955520u    // uint[NPTS*64]      = 8388608 (shp, fp16 pairs)
#define WS_BQPART   22566912u    // float[1024*3076]   = 12599296 (OVERLAYS self+shp;
                                 //   dead after k_finalize, before k_self writes)

typedef __attribute__((ext_vector_type(8))) _Float16 half8;
typedef __attribute__((ext_vector_type(2))) _Float16 half2v;
typedef __attribute__((ext_vector_type(4))) float floatx4;
typedef __attribute__((ext_vector_type(16))) float floatx16;

__device__ __forceinline__ unsigned short f2h_bits(float f) {
    _Float16 h = (_Float16)f;
    return *reinterpret_cast<unsigned short*>(&h);
}
__device__ __forceinline__ float bf_lo(unsigned int w) { return __uint_as_float(w << 16); }
__device__ __forceinline__ float bf_hi(unsigned int w) { return __uint_as_float(w & 0xffff0000u); }
__device__ __forceinline__ unsigned int pack_bf2(float lo, float hi) {
    __hip_bfloat162 hh = __float22bfloat162_rn(make_float2(lo, hi));
    return *reinterpret_cast<unsigned int*>(&hh);
}
__device__ __forceinline__ unsigned int pack_h2(float lo, float hi) {
    half2v hh = { (_Float16)lo, (_Float16)hi };
    return *reinterpret_cast<unsigned int*>(&hh);
}

// ------------- fused prep + ball query (1056 blocks) ------------------------
// blocks 0-31:   sample pixmap inversion + W2 B-frag packs (16x16 and 32x32)
// blocks 32-1055: ballot-prefix ball query (32 samples x 32 chunks x 32 queries)
union ShBQ {
    struct {
        float2 poss[1024];
        float accd[1024], accx[1024], accy[1024];
        unsigned long long cand[4][256];
    } bq;                                             // 28672 B
    struct {
        int cntS[1024], preS[1024], offS[1024], pixOf[1024];
        int wtot[4];
    } pm;                                             // 16400 B
};

__launch_bounds__(256)
__global__ void k_bq(const float* __restrict__ pos,
                     int* __restrict__ nbrs, int* __restrict__ nbr_cnt,
                     float* __restrict__ bqpart,
                     const float* __restrict__ W2, unsigned short* __restrict__ w2b,
                     unsigned short* __restrict__ w2b32,
                     int* __restrict__ qcnt, int* __restrict__ qstart,
                     int* __restrict__ qlist, int* __restrict__ islot) {
    __shared__ ShBQ sh;
    int tid = threadIdx.x;

    if (blockIdx.x < 32) {
        // ---------------- prep path ----------------
        int s = blockIdx.x;
        int gt = s * 256 + tid;            // 8192 total
        {   // W2 pack (16x16 layout): B-frag lane L holds B[k=(L>>4)*8+j][n=L&15]
            int j  = gt & 7;
            int L  = (gt >> 3) & 63;
            int ks = (gt >> 9) & 3;
            int t4 = gt >> 11;
            int k = ks * 32 + (L >> 4) * 8 + j;
            int n = t4 * 16 + (L & 15);
            w2b[gt] = f2h_bits(W2[k * 64 + n]);
        }
        {   // W2 pack (32x32 layout): pair p=ks*2+nh, lane L holds
            // B[k=ks*16+(L>>5)*8+j][n=nh*32+(L&31)]
            int j  = gt & 7;
            int L  = (gt >> 3) & 63;
            int p  = gt >> 9;              // 0..15
            int ks = p >> 1, nh = p & 1;
            int k = ks * 16 + (L >> 5) * 8 + j;
            int n = nh * 32 + (L & 31);
            w2b32[gt] = f2h_bits(W2[k * 64 + n]);
        }
        int base = s << 10;
        for (int i = tid; i < 1024; i += 256) sh.pm.cntS[i] = 0;
        __syncthreads();
        for (int ql = tid; ql < 1024; ql += 256) {
            float2 p = *(const float2*)&pos[2 * (base + ql)];
            int row = min(max((int)(p.y * 32.0f), 0), 31);
            int col = min(max((int)(p.x * 32.0f), 0), 31);
            int pixl = row * 32 + col;
            sh.pm.pixOf[ql] = pixl;
            atomicAdd(&sh.pm.cntS[pixl], 1);
        }
        __syncthreads();
        int a0 = sh.pm.cntS[4 * tid], a1 = sh.pm.cntS[4 * tid + 1];
        int a2 = sh.pm.cntS[4 * tid + 2], a3 = sh.pm.cntS[4 * tid + 3];
        int tsum = a0 + a1 + a2 + a3;
        int lane = tid & 63, wv = tid >> 6;
        int v = tsum;
        for (int o = 1; o < 64; o <<= 1) { int u = __shfl_up(v, o); if (lane >= o) v += u; }
        if (lane == 63) sh.pm.wtot[wv] = v;
        __syncthreads();
        int wbase = 0;
        for (int w = 0; w < wv; ++w) wbase += sh.pm.wtot[w];
        int excl = wbase + v - tsum;
        sh.pm.preS[4 * tid] = excl;
        sh.pm.preS[4 * tid + 1] = excl + a0;
        sh.pm.preS[4 * tid + 2] = excl + a0 + a1;
        sh.pm.preS[4 * tid + 3] = excl + a0 + a1 + a2;
        __syncthreads();
        for (int i = tid; i < 1024; i += 256) sh.pm.offS[i] = sh.pm.preS[i];
        __syncthreads();
        for (int ql = tid; ql < 1024; ql += 256) {
            int p = sh.pm.pixOf[ql];
            int slot = atomicAdd(&sh.pm.offS[p], 1);
            qlist[base + slot] = base + ql;
            islot[base + ql] = base + slot;
        }
        for (int i = tid; i < 1024; i += 256) {
            qcnt[base + i] = sh.pm.cntS[i];
            qstart[base + i] = base + sh.pm.preS[i];
        }
        return;
    }

    // ---------------- ball query path ----------------
    int bqphys = blockIdx.x - 32;      // 0..1023; physical XCD = bqphys & 7
    int bqid = (bqphys & 7) * 128 + (bqphys >> 3);   // XCD x owns samples [4x,4x+4)
    int wave = tid >> 6, lane = tid & 63;
    int s = bqid >> 5;                 // sample
    int chunk = bqid & 31;             // 32 chunks of 32 queries
    int base = s << 10;
    for (int i = tid; i < 1024; i += 256) sh.bq.poss[i] = *(const float2*)&pos[2 * (base + i)];
    for (int i = tid; i < 1024; i += 256) { sh.bq.accd[i] = 0.0f; sh.bq.accx[i] = 0.0f; sh.bq.accy[i] = 0.0f; }
    __syncthreads();
    float2 pr[16];
#pragma unroll
    for (int k = 0; k < 16; ++k) pr[k] = sh.bq.poss[k * 64 + lane];
    unsigned long long lb = (1ull << lane) - 1ull;   // bits below this lane

    float aD = 0, aE = 0, aF = 0;
    for (int qi = 0; qi < 8; ++qi) {
        int ql = chunk * 32 + wave * 8 + qi;
        int q = base + ql;
        float2 qp = sh.bq.poss[ql];
        int row = min(max((int)(qp.y * 32.0f), 0), 31);
        int col = min(max((int)(qp.x * 32.0f), 0), 31);
        int pixl = row * 32 + col;
        float2 tp = sh.bq.poss[pixl];
        int cnt = 0;
        __builtin_amdgcn_wave_barrier();
#pragma unroll
        for (int k = 0; k < 16; ++k) {
            float dx = pr[k].x - qp.x, dy = pr[k].y - qp.y;
            float d2 = __fadd_rn(__fmul_rn(dx, dx), __fmul_rn(dy, dy)); // no FMA contraction
            bool pred = (d2 <= 0.01f);
            unsigned long long mask = __ballot(pred);
            if (pred) {
                int slot = cnt + (int)__popcll(mask & lb);
                if (slot < 256)
                    sh.bq.cand[wave][slot] = ((unsigned long long)__float_as_uint(d2) << 32)
                                             | (unsigned int)(k * 64 + lane);
            }
            cnt += (int)__popcll(mask);
        }
        cnt = min(cnt, 256);
        __builtin_amdgcn_wave_barrier();
        int osel = 0;
        for (int cb = 0; cb < cnt; cb += 64) {
            int i = cb + lane;
            bool sel = false;
            int j = 0;
            if (i < cnt) {
                unsigned long long key = sh.bq.cand[wave][i];
                j = (int)(key & 0xffffffffu);
                if (cnt <= KNB) {
                    sel = (j != pixl);                 // all in-radius are top-K
                } else {
                    int rank = 0;
                    for (int t = 0; t < cnt; ++t) rank += (sh.bq.cand[wave][t] < key) ? 1 : 0;
                    sel = (rank < KNB) && (j != pixl); // top-K, then remove_self_loops
                }
            }
            unsigned long long mask = __ballot(sel);
            if (sel) {
                int slot = osel + (int)__popcll(mask & lb);
                nbrs[q * KNB + slot] = base + j;
                float rx = sh.bq.poss[j].x - tp.x, ry = sh.bq.poss[j].y - tp.y;
                aD += rx * rx; aE += rx * ry; aF += ry * ry;
                atomicAdd(&sh.bq.accd[j], 1.0f);
                atomicAdd(&sh.bq.accx[j], tp.x);
                atomicAdd(&sh.bq.accy[j], tp.y);
            }
            osel += (int)__popcll(mask);
        }
        // pad unused slots with a safe in-sample index so k_out can load
        // nbrs rows unconditionally (breaks the cnt->nbrs serial chain)
        if (lane >= osel && lane < KNB) nbrs[q * KNB + lane] = base;
        if (lane == 0) nbr_cnt[q] = osel;
    }
#pragma unroll
    for (int o = 1; o < 64; o <<= 1) {
        aD += __shfl_xor(aD, o); aE += __shfl_xor(aE, o); aF += __shfl_xor(aF, o);
    }
    __syncthreads();
    float* pb = &bqpart[bqid * 3076];
    for (int i = tid; i < 1024; i += 256) {
        pb[i] = sh.bq.accd[i]; pb[1024 + i] = sh.bq.accx[i]; pb[2048 + i] = sh.bq.accy[i];
    }
    if (tid == 0) { pb[3072] = aD; pb[3073] = aE; pb[3074] = aF; }   // DEF tails, plain store
}

// ---------------- node GEMM1 + fused nodeagg + BN node-stats ----------------
// 256 blocks x 512 threads (8 waves); block = 128 nodes; lane owns f0=2l, f1=2l+1.
__launch_bounds__(512)
__global__ void k_y(const float* __restrict__ x, const float* __restrict__ W1,
                    const float* __restrict__ b1, const float* __restrict__ pos,
                    const float* __restrict__ bqpart,
                    unsigned int* __restrict__ yb, float* __restrict__ partials) {
    __shared__ float w1s[64 * 128];
    __shared__ float stage[8][512];
    __shared__ float lsum[515];
    __shared__ float degS[128], stxS[128], styS[128];
    int tid = threadIdx.x;
    int vb = (blockIdx.x & 7) * 32 + (blockIdx.x >> 3);   // XCD-chunked: XCD x -> samples [4x,4x+4)
    int nblock = vb * 128;
    for (int i = tid; i < 64 * 128; i += 512) w1s[i] = W1[i];
    for (int i = tid; i < 515; i += 512) lsum[i] = 0.0f;
    if (tid < 128) {                       // fused nodeagg: 32 chunk partials
        int n = nblock + tid;
        int s = n >> 10, off = n & 1023;
        const float* pb = &bqpart[(s * 32) * 3076];
        float d = 0, xx = 0, yy = 0;
        for (int j = 0; j < 32; ++j) {
            d  += pb[j * 3076 + off];
            xx += pb[j * 3076 + 1024 + off];
            yy += pb[j * 3076 + 2048 + off];
        }
        degS[tid] = d; stxS[tid] = xx; styS[tid] = yy;
    }
    __syncthreads();
    int wave = tid >> 6, lane = tid & 63;
    int f0 = 2 * lane, f1 = 2 * lane + 1;
    float b10 = b1[f0], b11 = b1[f1];
    float* st = &stage[wave][0];
    float P0 = 0, Q0 = 0, R0 = 0, S0 = 0, P1 = 0, Q1 = 0, R1 = 0, S1 = 0;
    float sB = 0, sC = 0, sDeg = 0;

    for (int it = 0; it < 2; ++it) {
        int nbase = nblock + (wave * 2 + it) * 8;
        __builtin_amdgcn_wave_barrier();
#pragma unroll
        for (int mm = 0; mm < 8; ++mm)
            st[mm * 64 + lane] = x[(nbase + mm) * 64 + lane];
        __builtin_amdgcn_wave_barrier();
        float z0[8], z1[8];
#pragma unroll
        for (int mm = 0; mm < 8; ++mm) { z0[mm] = b10; z1[mm] = b11; }
        for (int k4 = 0; k4 < 16; ++k4) {
            float2 wv0 = *(const float2*)&w1s[(k4 * 4 + 0) * 128 + f0];
            float2 wv1 = *(const float2*)&w1s[(k4 * 4 + 1) * 128 + f0];
            float2 wv2 = *(const float2*)&w1s[(k4 * 4 + 2) * 128 + f0];
            float2 wv3 = *(const float2*)&w1s[(k4 * 4 + 3) * 128 + f0];
#pragma unroll
            for (int mm = 0; mm < 8; ++mm) {
                float4 mk = *(const float4*)&st[mm * 64 + k4 * 4];
                z0[mm] += mk.x * wv0.x + mk.y * wv1.x + mk.z * wv2.x + mk.w * wv3.x;
                z1[mm] += mk.x * wv0.y + mk.y * wv1.y + mk.z * wv2.y + mk.w * wv3.y;
            }
        }
#pragma unroll
        for (int mm = 0; mm < 8; ++mm) {
            int n = nbase + mm;
            int li = n - nblock;
            float dg = degS[li];
            float wgt = 1.0f + dg;
            float Bn = dg * pos[2 * n]     - stxS[li];
            float Cn = dg * pos[2 * n + 1] - styS[li];
            float a = z0[mm], bq = z1[mm];
            P0 += wgt * a;  Q0 += wgt * a * a;  R0 += a * Bn;  S0 += a * Cn;
            P1 += wgt * bq; Q1 += wgt * bq * bq; R1 += bq * Bn; S1 += bq * Cn;
            sB += Bn; sC += Cn; sDeg += dg;
            yb[n * 64 + lane] = pack_bf2(a, bq);
        }
        __builtin_amdgcn_wave_barrier();
    }
    atomicAdd(&lsum[f0], P0);        atomicAdd(&lsum[f1], P1);
    atomicAdd(&lsum[128 + f0], Q0);  atomicAdd(&lsum[128 + f1], Q1);
    atomicAdd(&lsum[256 + f0], R0);  atomicAdd(&lsum[256 + f1], R1);
    atomicAdd(&lsum[384 + f0], S0);  atomicAdd(&lsum[384 + f1], S1);
    if (lane == 0) {
        atomicAdd(&lsum[512], sB);
        atomicAdd(&lsum[513], sC);
        atomicAdd(&lsum[514], sDeg);
    }
    __syncthreads();
    for (int i = tid; i < 515; i += 512) partials[blockIdx.x * 516 + i] = lsum[i];
}

// --------------------------- finalize BN scale/shift ------------------------
__global__ void k_finalize(const float* __restrict__ gamma, const float* __restrict__ beta,
                           const float* __restrict__ W1, const float* __restrict__ partials,
                           const float* __restrict__ bqpart, float* __restrict__ scsh) {
    __shared__ float red[515];
    __shared__ float sDEF[3];
    int tid = threadIdx.x;    // 256
    if (tid < 3) sDEF[tid] = 0.0f;
    for (int i = tid; i < 515; i += 256) {
        float s = 0;
        for (int b = 0; b < 256; ++b) s += partials[b * 516 + i];
        red[i] = s;
    }
    __syncthreads();
    {   // sum the 1024 per-block DEF tails
        float td = 0, te = 0, tf = 0;
        for (int b = tid; b < 1024; b += 256) {
            const float* pb = &bqpart[b * 3076 + 3072];
            td += pb[0]; te += pb[1]; tf += pb[2];
        }
        atomicAdd(&sDEF[0], td); atomicAdd(&sDEF[1], te); atomicAdd(&sDEF[2], tf);
    }
    __syncthreads();
    if (tid < 128) {
        int f = tid;
        float P = red[f], Q = red[128 + f], R = red[256 + f], S = red[384 + f];
        float SB = red[512], SC = red[513], SDeg = red[514];
        float u = W1[8192 + f], v = W1[8320 + f];
        float cntv = 32768.0f + SDeg;
        float mean = (P + u * SB + v * SC) / cntv;
        float E2 = (Q + 2.0f * u * R + 2.0f * v * S
                    + u * u * sDEF[0] + 2.0f * u * v * sDEF[1] + v * v * sDEF[2]) / cntv;
        float var = E2 - mean * mean;
        float sc = gamma[f] / sqrtf(var + BN_EPS);
        scsh[f] = sc;
        scsh[128 + f] = beta[f] - mean * sc;
    }
}

// ---------- self pass (MFMA f16) + w/shp precompute (fp16) ------------------
__launch_bounds__(256)
__global__ void k_self(const unsigned int* __restrict__ yb, const float* __restrict__ pos,
                       const float* __restrict__ W1, const float* __restrict__ scsh,
                       const unsigned short* __restrict__ w2b, const float* __restrict__ b2,
                       const int* __restrict__ qcnt,
                       unsigned int* __restrict__ wbuf, unsigned int* __restrict__ shpbuf,
                       float* __restrict__ selfbuf, float* __restrict__ out) {
    __shared__ unsigned short hbuf[4][16 * 136];   // 272 B row stride
    int tid = threadIdx.x, wave = tid >> 6, lane = tid & 63;
    unsigned short* hb = hbuf[wave];
    half8 bfrag[4][4];
#pragma unroll
    for (int t = 0; t < 4; ++t)
#pragma unroll
        for (int ks = 0; ks < 4; ++ks)
            bfrag[t][ks] = *(const half8*)&w2b[((t * 4 + ks) * 64 + lane) * 8];
    int f0 = 2 * lane;
    float sc0 = scsh[f0],     sh0 = scsh[128 + f0];
    float sc1 = scsh[f0 + 1], sh1 = scsh[129 + f0];
    float u0 = W1[8192 + f0], v0 = W1[8320 + f0];
    float u1 = W1[8193 + f0], v1 = W1[8321 + f0];
    float b2v0 = b2[(lane & 15)],      b2v1 = b2[16 + (lane & 15)];
    float b2v2 = b2[32 + (lane & 15)], b2v3 = b2[48 + (lane & 15)];

    int vb = (blockIdx.x & 7) * 64 + (blockIdx.x >> 3);   // XCD-chunked node blocks
    int nbase = (vb * 4 + wave) * 16;
#pragma unroll
    for (int c = 0; c < 2; ++c) {
        unsigned int yw[8];
#pragma unroll
        for (int j = 0; j < 8; ++j)
            yw[j] = yb[(nbase + c * 8 + j) * 64 + lane];
#pragma unroll
        for (int j = 0; j < 8; ++j) {
            int e = c * 8 + j;
            int nn = nbase + e;
            float y0 = bf_lo(yw[j]), y1 = bf_hi(yw[j]);
            float h0 = fmaxf(y0 * sc0 + sh0, 0.0f);
            float h1 = fmaxf(y1 * sc1 + sh1, 0.0f);
            *(unsigned int*)&hb[e * 136 + f0] = pack_h2(h0, h1);
            float px = pos[2 * nn], py = pos[2 * nn + 1];
            float ts0 = (px * u0 + py * v0) * sc0;
            float ts1 = (px * u1 + py * v1) * sc1;
            wbuf[nn * 64 + lane]   = pack_h2(y0 * sc0 + ts0, y1 * sc1 + ts1);
            shpbuf[nn * 64 + lane] = pack_h2(sh0 - ts0, sh1 - ts1);
        }
    }
    __builtin_amdgcn_wave_barrier();
    floatx4 acc0 = {0,0,0,0}, acc1 = {0,0,0,0}, acc2 = {0,0,0,0}, acc3 = {0,0,0,0};
#pragma unroll
    for (int ks = 0; ks < 4; ++ks) {
        half8 a = *(const half8*)&hb[(lane & 15) * 136 + ks * 32 + (lane >> 4) * 8];
        acc0 = __builtin_amdgcn_mfma_f32_16x16x32_f16(a, bfrag[0][ks], acc0, 0, 0, 0);
        acc1 = __builtin_amdgcn_mfma_f32_16x16x32_f16(a, bfrag[1][ks], acc1, 0, 0, 0);
        acc2 = __builtin_amdgcn_mfma_f32_16x16x32_f16(a, bfrag[2][ks], acc2, 0, 0, 0);
        acc3 = __builtin_amdgcn_mfma_f32_16x16x32_f16(a, bfrag[3][ks], acc3, 0, 0, 0);
    }
    int nrow = nbase + (lane >> 4) * 4;
#pragma unroll
    for (int r = 0; r < 4; ++r) {
        int n = nrow + r;
        float o0 = acc0[r] + b2v0, o1 = acc1[r] + b2v1;
        float o2 = acc2[r] + b2v2, o3 = acc3[r] + b2v3;
        selfbuf[n * 64 + (lane & 15)]      = o0;   // contiguous copy for k_gather
        selfbuf[n * 64 + 16 + (lane & 15)] = o1;
        selfbuf[n * 64 + 32 + (lane & 15)] = o2;
        selfbuf[n * 64 + 48 + (lane & 15)] = o3;
        if (qcnt[n] == 0) {                 // k_gather overwrites qcnt>0 nodes
            int obase = (n >> 10) * 65536 + (n & 1023);
            out[obase + ((lane & 15)) * 1024]      = o0;
            out[obase + (16 + (lane & 15)) * 1024] = o1;
            out[obase + (32 + (lane & 15)) * 1024] = o2;
            out[obase + (48 + (lane & 15)) * 1024] = o3;
        }
    }
}

// ---------- neighbor pass: 32x32 MFMA, 1 query/wave, lane==edge row ---------
__launch_bounds__(256)
__global__ void k_out(const unsigned int* __restrict__ wbuf,
                      const unsigned int* __restrict__ shpbuf,
                      const float* __restrict__ pos,
                      const unsigned short* __restrict__ w2b32, const float* __restrict__ b2,
                      const int* __restrict__ nbrs, const int* __restrict__ nbr_cnt,
                      const int* __restrict__ islot, float* __restrict__ scratch) {
    int tid = threadIdx.x, wave = tid >> 6, lane = tid & 63;
    // B-frags (32x32x16): bfrag[ks][nh], lane l holds B[ks*16+(l>>5)*8+j][nh*32+(l&31)]
    half8 bfrag[8][2];
#pragma unroll
    for (int ks = 0; ks < 8; ++ks)
#pragma unroll
        for (int nh = 0; nh < 2; ++nh)
            bfrag[ks][nh] = *(const half8*)&w2b32[((ks * 2 + nh) * 64 + lane) * 8];
    float b2l = b2[lane];
    int kc = (lane >> 5) * 4;            // dword offset of this lane's k-chunk
    int vb = (blockIdx.x & 7) * 1024 + (blockIdx.x >> 3);  // XCD x -> samples [4x,4x+4)
    int q = vb * 4 + wave;               // one query per wave

    // ---- independent loads issued up front ----
    int m = nbr_cnt[q];
    int isq = islot[q];
    int nv = nbrs[q * KNB + (lane & 31)];   // rows fully padded by k_bq: safe
    float2 qp = *(const float2*)&pos[2 * q];

    // gather: lane l IS edge row l&31; 8 x dwordx4 covers K=128
    const unsigned int* wp = &wbuf[nv * 64 + kc];
    uint4 g[8];
#pragma unroll
    for (int ks = 0; ks < 8; ++ks) g[ks] = *(const uint4*)&wp[ks * 8];

    int row = min(max((int)(qp.y * 32.0f), 0), 31);
    int col = min(max((int)(qp.x * 32.0f), 0), 31);
    int pixq = ((q >> 10) << 10) + row * 32 + col;
    const unsigned int* sp = &shpbuf[pixq * 64 + kc];
    uint4 sv[8];
#pragma unroll
    for (int ks = 0; ks < 8; ++ks) sv[ks] = *(const uint4*)&sp[ks * 8];

    floatx16 acc0 = {}, acc1 = {};
    __builtin_amdgcn_s_setprio(1);
#pragma unroll
    for (int ks = 0; ks < 8; ++ks) {
        union { unsigned int u[4]; half8 h8; } af;
        uint4 gg = g[ks], ss = sv[ks];
#pragma unroll
        for (int qd = 0; qd < 4; ++qd) {
            unsigned int wd = (qd == 0) ? gg.x : (qd == 1) ? gg.y : (qd == 2) ? gg.z : gg.w;
            unsigned int sd = (qd == 0) ? ss.x : (qd == 1) ? ss.y : (qd == 2) ? ss.z : ss.w;
            half2v wh = *reinterpret_cast<half2v*>(&wd);
            half2v shh = *reinterpret_cast<half2v*>(&sd);
            half2v zz = { (_Float16)0.0f, (_Float16)0.0f };
            half2v hh = __builtin_elementwise_max(wh + shh, zz);
            af.u[qd] = *reinterpret_cast<unsigned int*>(&hh);
        }
        acc0 = __builtin_amdgcn_mfma_f32_32x32x16_f16(af.h8, bfrag[ks][0], acc0, 0, 0, 0);
        acc1 = __builtin_amdgcn_mfma_f32_32x32x16_f16(af.h8, bfrag[ks][1], acc1, 0, 0, 0);
    }
    __builtin_amdgcn_s_setprio(0);

    // masked max over edge rows: acc reg i covers row (i&3)+8*(i>>2)+4*(lane>>5)
    int rbase = 4 * (lane >> 5);
    float v0 = -INFINITY, v1 = -INFINITY;
#pragma unroll
    for (int i = 0; i < 16; ++i) {
        int r = (i & 3) + 8 * (i >> 2) + rbase;
        bool ok = r < m;
        v0 = fmaxf(v0, ok ? acc0[i] : -INFINITY);
        v1 = fmaxf(v1, ok ? acc1[i] : -INFINITY);
    }
    v0 = fmaxf(v0, __shfl_xor(v0, 32));
    v1 = fmaxf(v1, __shfl_xor(v1, 32));
    // feature of lane l: l<32 -> l (from acc0 col l), l>=32 -> 32+(l&31) = l (acc1)
    float vf = ((lane < 32) ? v0 : v1) + b2l;   // m==0 -> -inf: ignored by k_gather
    scratch[isq * 64 + lane] = vf;              // coalesced 256B store, no atomics
}

// ---------- gather: per pixel, max(self, contiguous query slots) ------------
__launch_bounds__(256)
__global__ void k_gather(const float* __restrict__ scratch, const float* __restrict__ selfbuf,
                         const int* __restrict__ qcnt, const int* __restrict__ qstart,
                         float* __restrict__ out) {
    int tid = threadIdx.x, wave = tid >> 6, lane = tid & 63;
    int vb = (blockIdx.x & 7) * 1024 + (blockIdx.x >> 3);   // XCD-chunked nodes
    int n = vb * 4 + wave;
    int c = qcnt[n];
    if (c == 0) return;                  // out written by k_self
    int qs = qstart[n];
    float v = selfbuf[n * 64 + lane];
    for (int i = 0; i < c; ++i)
        v = fmaxf(v, scratch[(qs + i) * 64 + lane]);
    out[(n >> 10) * 65536 + lane * 1024 + (n & 1023)] = v;
}

extern "C" void kernel_launch(void* const* d_in, const int* in_sizes, int n_in,
                              void* d_out, int out_size, void* d_ws, size_t ws_size,
                              hipStream_t stream) {
    const float* x     = (const float*)d_in[0];
    const float* pos   = (const float*)d_in[1];
    // d_in[2] = batch (unused: points are sorted, b = idx >> 10)
    const float* W1    = (const float*)d_in[3];
    const float* b1    = (const float*)d_in[4];
    const float* gamma = (const float*)d_in[5];
    const float* beta  = (const float*)d_in[6];
    const float* W2    = (const float*)d_in[7];
    const float* b2    = (const float*)d_in[8];
    float* out = (float*)d_out;
    char* ws = (char*)d_ws;
    int*   nbrs     = (int*)(ws + WS_NBRS);
    int*   nbr_cnt  = (int*)(ws + WS_NBRCNT);
    float* scsh     = (float*)(ws + WS_SCSH);
    unsigned short* w2b = (unsigned short*)(ws + WS_W2B);
    unsigned short* w2b32 = (unsigned short*)(ws + WS_W2B32);
    float* partials = (float*)(ws + WS_PART);
    unsigned int* yb = (unsigned int*)(ws + WS_Y);
    float* scratch  = (float*)(ws + WS_SCRATCH);        // overlays yb (dead after k_self)
    unsigned int* wbuf = (unsigned int*)(ws + WS_WB);
    int* qcnt   = (int*)(ws + WS_QCNT);
    int* qstart = (int*)(ws + WS_QSTART);
    int* qlist  = (int*)(ws + WS_QLIST);
    int* islot  = (int*)(ws + WS_ISLOT);
    float* selfbuf = (float*)(ws + WS_SELF);
    unsigned int* shpbuf = (unsigned int*)(ws + WS_SHP);
    float* bqpart   = (float*)(ws + WS_BQPART);         // overlays self+shp (dead before k_self)

    k_bq<<<1056, 256, 0, stream>>>(pos, nbrs, nbr_cnt, bqpart, W2, w2b, w2b32,
                                   qcnt, qstart, qlist, islot);
    k_y<<<256, 512, 0, stream>>>(x, W1, b1, pos, bqpart, yb, partials);
    k_finalize<<<1, 256, 0, stream>>>(gamma, beta, W1, partials, bqpart, scsh);
    k_self<<<NPTS / 64, 256, 0, stream>>>(yb, pos, W1, scsh, w2b, b2, qcnt,
                                          wbuf, shpbuf, selfbuf, out);
    k_out<<<NPTS / 4, 256, 0, stream>>>(wbuf, shpbuf, pos, w2b32, b2,
                                        nbrs, nbr_cnt, islot, scratch);
    k_gather<<<NPTS / 4, 256, 0, stream>>>(scratch, selfbuf, qcnt, qstart, out);
}

// Round 4
// 238.033 us; speedup vs baseline: 1.0471x; 1.0471x over previous
//
#include <hip/hip_runtime.h>
#include <hip/hip_bf16.h>
#include <hip/hip_fp16.h>
#include <math.h>

// ---------------------------------------------------------------------------
// PointsToImage: ball-query (K=32, R=0.1) -> PointNetConv msg=[x_j, pos_j-pos_dst]
// -> Linear(66,128) -> masked-BatchNorm -> ReLU -> Linear(128,64) -> scatter-max
// into pixel nodes, output [B=32, F=64, 32, 32] fp32.
//
// R16: k_out MLP pass. R15 post-mortem: per-wave fixed overhead F~325cy,
// per-query V~794cy (mostly exposed gather latency); 1 query/wave doubled
// total F and killed cross-query MLP -> regression. Fix: keep verified 32x32
// MFMA path, 4 queries/wave + depth-2 pipeline on the divergent wbuf gathers
// (issue q_{i+1}'s 8 gathers before consuming q_i); vectorized meta loads
// (int4 nbr_cnt/islot, float4 pos); __launch_bounds__(256,2) so the register
// allocator keeps both gather stages live instead of serializing to save VGPR.
// Grid NPTS/16 = 2048 blocks. No setprio (was added in the regressing round).
// Pipeline (6 launches): k_bq -> k_y -> k_finalize -> k_self -> k_out -> k_gather
// ---------------------------------------------------------------------------

#define NPTS   32768
#define KNB    32
#define BN_EPS 1e-5f

// workspace layout (bytes) -- same envelope as R11 (max 39,344,128)
#define WS_NBRS     0u           // int[NPTS*KNB]      = 4194304
#define WS_NBRCNT   4194304u     // int[NPTS]          = 131072
#define WS_W2B32    4325376u     // ushort[8192]       (W2 B-frag, fp16, 32x32 layout)
#define WS_SCSH     4719616u     // float[256]
#define WS_W2B      4720640u     // ushort[8192]       (W2 B-frag, fp16, 16x16 layout)
#define WS_PART     4737024u     // float[256*516]     = 528384
#define WS_Y        5265408u     // uint[NPTS*64]      = 8388608 (yb; dead after k_self)
#define WS_SCRATCH  5265408u     // float[NPTS*64]     (OVERLAYS yb)
#define WS_WB       13654016u    // uint[NPTS*64]      = 8388608 (w, fp16 pairs)
#define WS_QCNT     22042624u    // int[NPTS]
#define WS_QSTART   22173696u    // int[NPTS]
#define WS_QLIST    22304768u    // int[NPTS]
#define WS_ISLOT    22435840u    // int[NPTS]
#define WS_SELF     22566912u    // float[NPTS*64]     = 8388608
#define WS_SHP      30955520u    // uint[NPTS*64]      = 8388608 (shp, fp16 pairs)
#define WS_BQPART   22566912u    // float[1024*3076]   = 12599296 (OVERLAYS self+shp;
                                 //   dead after k_finalize, before k_self writes)

typedef __attribute__((ext_vector_type(8))) _Float16 half8;
typedef __attribute__((ext_vector_type(2))) _Float16 half2v;
typedef __attribute__((ext_vector_type(4))) float floatx4;
typedef __attribute__((ext_vector_type(16))) float floatx16;

__device__ __forceinline__ unsigned short f2h_bits(float f) {
    _Float16 h = (_Float16)f;
    return *reinterpret_cast<unsigned short*>(&h);
}
__device__ __forceinline__ float bf_lo(unsigned int w) { return __uint_as_float(w << 16); }
__device__ __forceinline__ float bf_hi(unsigned int w) { return __uint_as_float(w & 0xffff0000u); }
__device__ __forceinline__ unsigned int pack_bf2(float lo, float hi) {
    __hip_bfloat162 hh = __float22bfloat162_rn(make_float2(lo, hi));
    return *reinterpret_cast<unsigned int*>(&hh);
}
__device__ __forceinline__ unsigned int pack_h2(float lo, float hi) {
    half2v hh = { (_Float16)lo, (_Float16)hi };
    return *reinterpret_cast<unsigned int*>(&hh);
}

// ------------- fused prep + ball query (1056 blocks) ------------------------
// blocks 0-31:   sample pixmap inversion + W2 B-frag packs (16x16 and 32x32)
// blocks 32-1055: ballot-prefix ball query (32 samples x 32 chunks x 32 queries)
union ShBQ {
    struct {
        float2 poss[1024];
        float accd[1024], accx[1024], accy[1024];
        unsigned long long cand[4][256];
    } bq;                                             // 28672 B
    struct {
        int cntS[1024], preS[1024], offS[1024], pixOf[1024];
        int wtot[4];
    } pm;                                             // 16400 B
};

__launch_bounds__(256)
__global__ void k_bq(const float* __restrict__ pos,
                     int* __restrict__ nbrs, int* __restrict__ nbr_cnt,
                     float* __restrict__ bqpart,
                     const float* __restrict__ W2, unsigned short* __restrict__ w2b,
                     unsigned short* __restrict__ w2b32,
                     int* __restrict__ qcnt, int* __restrict__ qstart,
                     int* __restrict__ qlist, int* __restrict__ islot) {
    __shared__ ShBQ sh;
    int tid = threadIdx.x;

    if (blockIdx.x < 32) {
        // ---------------- prep path ----------------
        int s = blockIdx.x;
        int gt = s * 256 + tid;            // 8192 total
        {   // W2 pack (16x16 layout): B-frag lane L holds B[k=(L>>4)*8+j][n=L&15]
            int j  = gt & 7;
            int L  = (gt >> 3) & 63;
            int ks = (gt >> 9) & 3;
            int t4 = gt >> 11;
            int k = ks * 32 + (L >> 4) * 8 + j;
            int n = t4 * 16 + (L & 15);
            w2b[gt] = f2h_bits(W2[k * 64 + n]);
        }
        {   // W2 pack (32x32 layout): pair p=ks*2+nh, lane L holds
            // B[k=ks*16+(L>>5)*8+j][n=nh*32+(L&31)]
            int j  = gt & 7;
            int L  = (gt >> 3) & 63;
            int p  = gt >> 9;              // 0..15
            int ks = p >> 1, nh = p & 1;
            int k = ks * 16 + (L >> 5) * 8 + j;
            int n = nh * 32 + (L & 31);
            w2b32[gt] = f2h_bits(W2[k * 64 + n]);
        }
        int base = s << 10;
        for (int i = tid; i < 1024; i += 256) sh.pm.cntS[i] = 0;
        __syncthreads();
        for (int ql = tid; ql < 1024; ql += 256) {
            float2 p = *(const float2*)&pos[2 * (base + ql)];
            int row = min(max((int)(p.y * 32.0f), 0), 31);
            int col = min(max((int)(p.x * 32.0f), 0), 31);
            int pixl = row * 32 + col;
            sh.pm.pixOf[ql] = pixl;
            atomicAdd(&sh.pm.cntS[pixl], 1);
        }
        __syncthreads();
        int a0 = sh.pm.cntS[4 * tid], a1 = sh.pm.cntS[4 * tid + 1];
        int a2 = sh.pm.cntS[4 * tid + 2], a3 = sh.pm.cntS[4 * tid + 3];
        int tsum = a0 + a1 + a2 + a3;
        int lane = tid & 63, wv = tid >> 6;
        int v = tsum;
        for (int o = 1; o < 64; o <<= 1) { int u = __shfl_up(v, o); if (lane >= o) v += u; }
        if (lane == 63) sh.pm.wtot[wv] = v;
        __syncthreads();
        int wbase = 0;
        for (int w = 0; w < wv; ++w) wbase += sh.pm.wtot[w];
        int excl = wbase + v - tsum;
        sh.pm.preS[4 * tid] = excl;
        sh.pm.preS[4 * tid + 1] = excl + a0;
        sh.pm.preS[4 * tid + 2] = excl + a0 + a1;
        sh.pm.preS[4 * tid + 3] = excl + a0 + a1 + a2;
        __syncthreads();
        for (int i = tid; i < 1024; i += 256) sh.pm.offS[i] = sh.pm.preS[i];
        __syncthreads();
        for (int ql = tid; ql < 1024; ql += 256) {
            int p = sh.pm.pixOf[ql];
            int slot = atomicAdd(&sh.pm.offS[p], 1);
            qlist[base + slot] = base + ql;
            islot[base + ql] = base + slot;
        }
        for (int i = tid; i < 1024; i += 256) {
            qcnt[base + i] = sh.pm.cntS[i];
            qstart[base + i] = base + sh.pm.preS[i];
        }
        return;
    }

    // ---------------- ball query path ----------------
    int bqphys = blockIdx.x - 32;      // 0..1023; physical XCD = bqphys & 7
    int bqid = (bqphys & 7) * 128 + (bqphys >> 3);   // XCD x owns samples [4x,4x+4)
    int wave = tid >> 6, lane = tid & 63;
    int s = bqid >> 5;                 // sample
    int chunk = bqid & 31;             // 32 chunks of 32 queries
    int base = s << 10;
    for (int i = tid; i < 1024; i += 256) sh.bq.poss[i] = *(const float2*)&pos[2 * (base + i)];
    for (int i = tid; i < 1024; i += 256) { sh.bq.accd[i] = 0.0f; sh.bq.accx[i] = 0.0f; sh.bq.accy[i] = 0.0f; }
    __syncthreads();
    float2 pr[16];
#pragma unroll
    for (int k = 0; k < 16; ++k) pr[k] = sh.bq.poss[k * 64 + lane];
    unsigned long long lb = (1ull << lane) - 1ull;   // bits below this lane

    float aD = 0, aE = 0, aF = 0;
    for (int qi = 0; qi < 8; ++qi) {
        int ql = chunk * 32 + wave * 8 + qi;
        int q = base + ql;
        float2 qp = sh.bq.poss[ql];
        int row = min(max((int)(qp.y * 32.0f), 0), 31);
        int col = min(max((int)(qp.x * 32.0f), 0), 31);
        int pixl = row * 32 + col;
        float2 tp = sh.bq.poss[pixl];
        int cnt = 0;
        __builtin_amdgcn_wave_barrier();
#pragma unroll
        for (int k = 0; k < 16; ++k) {
            float dx = pr[k].x - qp.x, dy = pr[k].y - qp.y;
            float d2 = __fadd_rn(__fmul_rn(dx, dx), __fmul_rn(dy, dy)); // no FMA contraction
            bool pred = (d2 <= 0.01f);
            unsigned long long mask = __ballot(pred);
            if (pred) {
                int slot = cnt + (int)__popcll(mask & lb);
                if (slot < 256)
                    sh.bq.cand[wave][slot] = ((unsigned long long)__float_as_uint(d2) << 32)
                                             | (unsigned int)(k * 64 + lane);
            }
            cnt += (int)__popcll(mask);
        }
        cnt = min(cnt, 256);
        __builtin_amdgcn_wave_barrier();
        int osel = 0;
        for (int cb = 0; cb < cnt; cb += 64) {
            int i = cb + lane;
            bool sel = false;
            int j = 0;
            if (i < cnt) {
                unsigned long long key = sh.bq.cand[wave][i];
                j = (int)(key & 0xffffffffu);
                if (cnt <= KNB) {
                    sel = (j != pixl);                 // all in-radius are top-K
                } else {
                    int rank = 0;
                    for (int t = 0; t < cnt; ++t) rank += (sh.bq.cand[wave][t] < key) ? 1 : 0;
                    sel = (rank < KNB) && (j != pixl); // top-K, then remove_self_loops
                }
            }
            unsigned long long mask = __ballot(sel);
            if (sel) {
                int slot = osel + (int)__popcll(mask & lb);
                nbrs[q * KNB + slot] = base + j;
                float rx = sh.bq.poss[j].x - tp.x, ry = sh.bq.poss[j].y - tp.y;
                aD += rx * rx; aE += rx * ry; aF += ry * ry;
                atomicAdd(&sh.bq.accd[j], 1.0f);
                atomicAdd(&sh.bq.accx[j], tp.x);
                atomicAdd(&sh.bq.accy[j], tp.y);
            }
            osel += (int)__popcll(mask);
        }
        // pad unused slots with a safe in-sample index so k_out can load
        // nbrs rows unconditionally (breaks the cnt->nbrs serial chain)
        if (lane >= osel && lane < KNB) nbrs[q * KNB + lane] = base;
        if (lane == 0) nbr_cnt[q] = osel;
    }
#pragma unroll
    for (int o = 1; o < 64; o <<= 1) {
        aD += __shfl_xor(aD, o); aE += __shfl_xor(aE, o); aF += __shfl_xor(aF, o);
    }
    __syncthreads();
    float* pb = &bqpart[bqid * 3076];
    for (int i = tid; i < 1024; i += 256) {
        pb[i] = sh.bq.accd[i]; pb[1024 + i] = sh.bq.accx[i]; pb[2048 + i] = sh.bq.accy[i];
    }
    if (tid == 0) { pb[3072] = aD; pb[3073] = aE; pb[3074] = aF; }   // DEF tails, plain store
}

// ---------------- node GEMM1 + fused nodeagg + BN node-stats ----------------
// 256 blocks x 512 threads (8 waves); block = 128 nodes; lane owns f0=2l, f1=2l+1.
__launch_bounds__(512)
__global__ void k_y(const float* __restrict__ x, const float* __restrict__ W1,
                    const float* __restrict__ b1, const float* __restrict__ pos,
                    const float* __restrict__ bqpart,
                    unsigned int* __restrict__ yb, float* __restrict__ partials) {
    __shared__ float w1s[64 * 128];
    __shared__ float stage[8][512];
    __shared__ float lsum[515];
    __shared__ float degS[128], stxS[128], styS[128];
    int tid = threadIdx.x;
    int vb = (blockIdx.x & 7) * 32 + (blockIdx.x >> 3);   // XCD-chunked: XCD x -> samples [4x,4x+4)
    int nblock = vb * 128;
    for (int i = tid; i < 64 * 128; i += 512) w1s[i] = W1[i];
    for (int i = tid; i < 515; i += 512) lsum[i] = 0.0f;
    if (tid < 128) {                       // fused nodeagg: 32 chunk partials
        int n = nblock + tid;
        int s = n >> 10, off = n & 1023;
        const float* pb = &bqpart[(s * 32) * 3076];
        float d = 0, xx = 0, yy = 0;
        for (int j = 0; j < 32; ++j) {
            d  += pb[j * 3076 + off];
            xx += pb[j * 3076 + 1024 + off];
            yy += pb[j * 3076 + 2048 + off];
        }
        degS[tid] = d; stxS[tid] = xx; styS[tid] = yy;
    }
    __syncthreads();
    int wave = tid >> 6, lane = tid & 63;
    int f0 = 2 * lane, f1 = 2 * lane + 1;
    float b10 = b1[f0], b11 = b1[f1];
    float* st = &stage[wave][0];
    float P0 = 0, Q0 = 0, R0 = 0, S0 = 0, P1 = 0, Q1 = 0, R1 = 0, S1 = 0;
    float sB = 0, sC = 0, sDeg = 0;

    for (int it = 0; it < 2; ++it) {
        int nbase = nblock + (wave * 2 + it) * 8;
        __builtin_amdgcn_wave_barrier();
#pragma unroll
        for (int mm = 0; mm < 8; ++mm)
            st[mm * 64 + lane] = x[(nbase + mm) * 64 + lane];
        __builtin_amdgcn_wave_barrier();
        float z0[8], z1[8];
#pragma unroll
        for (int mm = 0; mm < 8; ++mm) { z0[mm] = b10; z1[mm] = b11; }
        for (int k4 = 0; k4 < 16; ++k4) {
            float2 wv0 = *(const float2*)&w1s[(k4 * 4 + 0) * 128 + f0];
            float2 wv1 = *(const float2*)&w1s[(k4 * 4 + 1) * 128 + f0];
            float2 wv2 = *(const float2*)&w1s[(k4 * 4 + 2) * 128 + f0];
            float2 wv3 = *(const float2*)&w1s[(k4 * 4 + 3) * 128 + f0];
#pragma unroll
            for (int mm = 0; mm < 8; ++mm) {
                float4 mk = *(const float4*)&st[mm * 64 + k4 * 4];
                z0[mm] += mk.x * wv0.x + mk.y * wv1.x + mk.z * wv2.x + mk.w * wv3.x;
                z1[mm] += mk.x * wv0.y + mk.y * wv1.y + mk.z * wv2.y + mk.w * wv3.y;
            }
        }
#pragma unroll
        for (int mm = 0; mm < 8; ++mm) {
            int n = nbase + mm;
            int li = n - nblock;
            float dg = degS[li];
            float wgt = 1.0f + dg;
            float Bn = dg * pos[2 * n]     - stxS[li];
            float Cn = dg * pos[2 * n + 1] - styS[li];
            float a = z0[mm], bq = z1[mm];
            P0 += wgt * a;  Q0 += wgt * a * a;  R0 += a * Bn;  S0 += a * Cn;
            P1 += wgt * bq; Q1 += wgt * bq * bq; R1 += bq * Bn; S1 += bq * Cn;
            sB += Bn; sC += Cn; sDeg += dg;
            yb[n * 64 + lane] = pack_bf2(a, bq);
        }
        __builtin_amdgcn_wave_barrier();
    }
    atomicAdd(&lsum[f0], P0);        atomicAdd(&lsum[f1], P1);
    atomicAdd(&lsum[128 + f0], Q0);  atomicAdd(&lsum[128 + f1], Q1);
    atomicAdd(&lsum[256 + f0], R0);  atomicAdd(&lsum[256 + f1], R1);
    atomicAdd(&lsum[384 + f0], S0);  atomicAdd(&lsum[384 + f1], S1);
    if (lane == 0) {
        atomicAdd(&lsum[512], sB);
        atomicAdd(&lsum[513], sC);
        atomicAdd(&lsum[514], sDeg);
    }
    __syncthreads();
    for (int i = tid; i < 515; i += 512) partials[blockIdx.x * 516 + i] = lsum[i];
}

// --------------------------- finalize BN scale/shift ------------------------
__global__ void k_finalize(const float* __restrict__ gamma, const float* __restrict__ beta,
                           const float* __restrict__ W1, const float* __restrict__ partials,
                           const float* __restrict__ bqpart, float* __restrict__ scsh) {
    __shared__ float red[515];
    __shared__ float sDEF[3];
    int tid = threadIdx.x;    // 256
    if (tid < 3) sDEF[tid] = 0.0f;
    for (int i = tid; i < 515; i += 256) {
        float s = 0;
        for (int b = 0; b < 256; ++b) s += partials[b * 516 + i];
        red[i] = s;
    }
    __syncthreads();
    {   // sum the 1024 per-block DEF tails
        float td = 0, te = 0, tf = 0;
        for (int b = tid; b < 1024; b += 256) {
            const float* pb = &bqpart[b * 3076 + 3072];
            td += pb[0]; te += pb[1]; tf += pb[2];
        }
        atomicAdd(&sDEF[0], td); atomicAdd(&sDEF[1], te); atomicAdd(&sDEF[2], tf);
    }
    __syncthreads();
    if (tid < 128) {
        int f = tid;
        float P = red[f], Q = red[128 + f], R = red[256 + f], S = red[384 + f];
        float SB = red[512], SC = red[513], SDeg = red[514];
        float u = W1[8192 + f], v = W1[8320 + f];
        float cntv = 32768.0f + SDeg;
        float mean = (P + u * SB + v * SC) / cntv;
        float E2 = (Q + 2.0f * u * R + 2.0f * v * S
                    + u * u * sDEF[0] + 2.0f * u * v * sDEF[1] + v * v * sDEF[2]) / cntv;
        float var = E2 - mean * mean;
        float sc = gamma[f] / sqrtf(var + BN_EPS);
        scsh[f] = sc;
        scsh[128 + f] = beta[f] - mean * sc;
    }
}

// ---------- self pass (MFMA f16) + w/shp precompute (fp16) ------------------
__launch_bounds__(256)
__global__ void k_self(const unsigned int* __restrict__ yb, const float* __restrict__ pos,
                       const float* __restrict__ W1, const float* __restrict__ scsh,
                       const unsigned short* __restrict__ w2b, const float* __restrict__ b2,
                       const int* __restrict__ qcnt,
                       unsigned int* __restrict__ wbuf, unsigned int* __restrict__ shpbuf,
                       float* __restrict__ selfbuf, float* __restrict__ out) {
    __shared__ unsigned short hbuf[4][16 * 136];   // 272 B row stride
    int tid = threadIdx.x, wave = tid >> 6, lane = tid & 63;
    unsigned short* hb = hbuf[wave];
    half8 bfrag[4][4];
#pragma unroll
    for (int t = 0; t < 4; ++t)
#pragma unroll
        for (int ks = 0; ks < 4; ++ks)
            bfrag[t][ks] = *(const half8*)&w2b[((t * 4 + ks) * 64 + lane) * 8];
    int f0 = 2 * lane;
    float sc0 = scsh[f0],     sh0 = scsh[128 + f0];
    float sc1 = scsh[f0 + 1], sh1 = scsh[129 + f0];
    float u0 = W1[8192 + f0], v0 = W1[8320 + f0];
    float u1 = W1[8193 + f0], v1 = W1[8321 + f0];
    float b2v0 = b2[(lane & 15)],      b2v1 = b2[16 + (lane & 15)];
    float b2v2 = b2[32 + (lane & 15)], b2v3 = b2[48 + (lane & 15)];

    int vb = (blockIdx.x & 7) * 64 + (blockIdx.x >> 3);   // XCD-chunked node blocks
    int nbase = (vb * 4 + wave) * 16;
#pragma unroll
    for (int c = 0; c < 2; ++c) {
        unsigned int yw[8];
#pragma unroll
        for (int j = 0; j < 8; ++j)
            yw[j] = yb[(nbase + c * 8 + j) * 64 + lane];
#pragma unroll
        for (int j = 0; j < 8; ++j) {
            int e = c * 8 + j;
            int nn = nbase + e;
            float y0 = bf_lo(yw[j]), y1 = bf_hi(yw[j]);
            float h0 = fmaxf(y0 * sc0 + sh0, 0.0f);
            float h1 = fmaxf(y1 * sc1 + sh1, 0.0f);
            *(unsigned int*)&hb[e * 136 + f0] = pack_h2(h0, h1);
            float px = pos[2 * nn], py = pos[2 * nn + 1];
            float ts0 = (px * u0 + py * v0) * sc0;
            float ts1 = (px * u1 + py * v1) * sc1;
            wbuf[nn * 64 + lane]   = pack_h2(y0 * sc0 + ts0, y1 * sc1 + ts1);
            shpbuf[nn * 64 + lane] = pack_h2(sh0 - ts0, sh1 - ts1);
        }
    }
    __builtin_amdgcn_wave_barrier();
    floatx4 acc0 = {0,0,0,0}, acc1 = {0,0,0,0}, acc2 = {0,0,0,0}, acc3 = {0,0,0,0};
#pragma unroll
    for (int ks = 0; ks < 4; ++ks) {
        half8 a = *(const half8*)&hb[(lane & 15) * 136 + ks * 32 + (lane >> 4) * 8];
        acc0 = __builtin_amdgcn_mfma_f32_16x16x32_f16(a, bfrag[0][ks], acc0, 0, 0, 0);
        acc1 = __builtin_amdgcn_mfma_f32_16x16x32_f16(a, bfrag[1][ks], acc1, 0, 0, 0);
        acc2 = __builtin_amdgcn_mfma_f32_16x16x32_f16(a, bfrag[2][ks], acc2, 0, 0, 0);
        acc3 = __builtin_amdgcn_mfma_f32_16x16x32_f16(a, bfrag[3][ks], acc3, 0, 0, 0);
    }
    int nrow = nbase + (lane >> 4) * 4;
#pragma unroll
    for (int r = 0; r < 4; ++r) {
        int n = nrow + r;
        float o0 = acc0[r] + b2v0, o1 = acc1[r] + b2v1;
        float o2 = acc2[r] + b2v2, o3 = acc3[r] + b2v3;
        selfbuf[n * 64 + (lane & 15)]      = o0;   // contiguous copy for k_gather
        selfbuf[n * 64 + 16 + (lane & 15)] = o1;
        selfbuf[n * 64 + 32 + (lane & 15)] = o2;
        selfbuf[n * 64 + 48 + (lane & 15)] = o3;
        if (qcnt[n] == 0) {                 // k_gather overwrites qcnt>0 nodes
            int obase = (n >> 10) * 65536 + (n & 1023);
            out[obase + ((lane & 15)) * 1024]      = o0;
            out[obase + (16 + (lane & 15)) * 1024] = o1;
            out[obase + (32 + (lane & 15)) * 1024] = o2;
            out[obase + (48 + (lane & 15)) * 1024] = o3;
        }
    }
}

// ---- neighbor pass: 32x32 MFMA, 4 queries/wave, depth-2 gather pipeline ----
__launch_bounds__(256, 2)
__global__ void k_out(const unsigned int* __restrict__ wbuf,
                      const unsigned int* __restrict__ shpbuf,
                      const float* __restrict__ pos,
                      const unsigned short* __restrict__ w2b32, const float* __restrict__ b2,
                      const int* __restrict__ nbrs, const int* __restrict__ nbr_cnt,
                      const int* __restrict__ islot, float* __restrict__ scratch) {
    int tid = threadIdx.x, wave = tid >> 6, lane = tid & 63;
    // B-frags (32x32x16): bfrag[ks][nh], lane l holds B[ks*16+(l>>5)*8+j][nh*32+(l&31)]
    half8 bfrag[8][2];
#pragma unroll
    for (int ks = 0; ks < 8; ++ks)
#pragma unroll
        for (int nh = 0; nh < 2; ++nh)
            bfrag[ks][nh] = *(const half8*)&w2b32[((ks * 2 + nh) * 64 + lane) * 8];
    float b2l = b2[lane];
    int kc = (lane >> 5) * 4;            // dword offset of this lane's k-chunk
    int vb = (blockIdx.x & 7) * 256 + (blockIdx.x >> 3);  // XCD x -> samples [4x,4x+4)
    int wid = vb * 4 + wave;             // 8192 waves, 4 queries each
    int qb = wid * 4;

    // ---- vectorized meta loads for all 4 queries ----
    int4 mv  = *(const int4*)&nbr_cnt[qb];
    int4 isv = *(const int4*)&islot[qb];
    int nv0 = nbrs[(qb + 0) * KNB + (lane & 31)];
    int nv1 = nbrs[(qb + 1) * KNB + (lane & 31)];
    int nv2 = nbrs[(qb + 2) * KNB + (lane & 31)];
    int nv3 = nbrs[(qb + 3) * KNB + (lane & 31)];
    float4 pA = *(const float4*)&pos[2 * qb];       // qp0.xy, qp1.xy
    float4 pB = *(const float4*)&pos[2 * qb + 4];   // qp2.xy, qp3.xy
    int sbase = (qb >> 10) << 10;
    int pixq0 = sbase + min(max((int)(pA.y * 32.0f), 0), 31) * 32 + min(max((int)(pA.x * 32.0f), 0), 31);
    int pixq1 = sbase + min(max((int)(pA.w * 32.0f), 0), 31) * 32 + min(max((int)(pA.z * 32.0f), 0), 31);
    int pixq2 = sbase + min(max((int)(pB.y * 32.0f), 0), 31) * 32 + min(max((int)(pB.x * 32.0f), 0), 31);
    int pixq3 = sbase + min(max((int)(pB.w * 32.0f), 0), 31) * 32 + min(max((int)(pB.z * 32.0f), 0), 31);

    uint4 gA[8], gB[8], sv[8];
    floatx16 acc0, acc1;

#define ISSUE_G(dst, nv) do {                                               \
        const unsigned int* wp_ = &wbuf[(nv) * 64 + kc];                    \
        _Pragma("unroll")                                                   \
        for (int ks_ = 0; ks_ < 8; ++ks_) dst[ks_] = *(const uint4*)&wp_[ks_ * 8]; \
    } while (0)

#define LOAD_SV(pixq) do {                                                  \
        const unsigned int* sp_ = &shpbuf[(pixq) * 64 + kc];                \
        _Pragma("unroll")                                                   \
        for (int ks_ = 0; ks_ < 8; ++ks_) sv[ks_] = *(const uint4*)&sp_[ks_ * 8]; \
    } while (0)

#define DO_MFMA(g) do {                                                     \
        acc0 = (floatx16){}; acc1 = (floatx16){};                           \
        _Pragma("unroll")                                                   \
        for (int ks_ = 0; ks_ < 8; ++ks_) {                                 \
            union { unsigned int u[4]; half8 h8; } af_;                     \
            uint4 gg_ = g[ks_], ss_ = sv[ks_];                              \
            _Pragma("unroll")                                               \
            for (int qd_ = 0; qd_ < 4; ++qd_) {                             \
                unsigned int wd_ = (qd_ == 0) ? gg_.x : (qd_ == 1) ? gg_.y  \
                                 : (qd_ == 2) ? gg_.z : gg_.w;              \
                unsigned int sd_ = (qd_ == 0) ? ss_.x : (qd_ == 1) ? ss_.y  \
                                 : (qd_ == 2) ? ss_.z : ss_.w;              \
                half2v wh_ = *reinterpret_cast<half2v*>(&wd_);              \
                half2v sh_ = *reinterpret_cast<half2v*>(&sd_);              \
                half2v zz_ = { (_Float16)0.0f, (_Float16)0.0f };            \
                half2v hh_ = __builtin_elementwise_max(wh_ + sh_, zz_);     \
                af_.u[qd_] = *reinterpret_cast<unsigned int*>(&hh_);        \
            }                                                               \
            acc0 = __builtin_amdgcn_mfma_f32_32x32x16_f16(af_.h8, bfrag[ks_][0], acc0, 0, 0, 0); \
            acc1 = __builtin_amdgcn_mfma_f32_32x32x16_f16(af_.h8, bfrag[ks_][1], acc1, 0, 0, 0); \
        }                                                                   \
    } while (0)

#define EPILOG(m, isq) do {                                                 \
        int rbase_ = 4 * (lane >> 5);                                       \
        float v0_ = -INFINITY, v1_ = -INFINITY;                             \
        _Pragma("unroll")                                                   \
        for (int i_ = 0; i_ < 16; ++i_) {                                   \
            int r_ = (i_ & 3) + 8 * (i_ >> 2) + rbase_;                     \
            bool ok_ = r_ < (m);                                            \
            v0_ = fmaxf(v0_, ok_ ? acc0[i_] : -INFINITY);                   \
            v1_ = fmaxf(v1_, ok_ ? acc1[i_] : -INFINITY);                   \
        }                                                                   \
        v0_ = fmaxf(v0_, __shfl_xor(v0_, 32));                              \
        v1_ = fmaxf(v1_, __shfl_xor(v1_, 32));                              \
        float vf_ = ((lane < 32) ? v0_ : v1_) + b2l;                        \
        scratch[(isq) * 64 + lane] = vf_;                                   \
    } while (0)

    // depth-2 pipeline: q_{i+1}'s divergent gathers in flight during q_i's MFMA
    ISSUE_G(gA, nv0);
    ISSUE_G(gB, nv1);
    LOAD_SV(pixq0); DO_MFMA(gA); EPILOG(mv.x, isv.x);
    ISSUE_G(gA, nv2);
    LOAD_SV(pixq1); DO_MFMA(gB); EPILOG(mv.y, isv.y);
    ISSUE_G(gB, nv3);
    LOAD_SV(pixq2); DO_MFMA(gA); EPILOG(mv.z, isv.z);
    LOAD_SV(pixq3); DO_MFMA(gB); EPILOG(mv.w, isv.w);

#undef ISSUE_G
#undef LOAD_SV
#undef DO_MFMA
#undef EPILOG
}

// ---------- gather: per pixel, max(self, contiguous query slots) ------------
__launch_bounds__(256)
__global__ void k_gather(const float* __restrict__ scratch, const float* __restrict__ selfbuf,
                         const int* __restrict__ qcnt, const int* __restrict__ qstart,
                         float* __restrict__ out) {
    int tid = threadIdx.x, wave = tid >> 6, lane = tid & 63;
    int vb = (blockIdx.x & 7) * 1024 + (blockIdx.x >> 3);   // XCD-chunked nodes
    int n = vb * 4 + wave;
    int c = qcnt[n];
    if (c == 0) return;                  // out written by k_self
    int qs = qstart[n];
    float v = selfbuf[n * 64 + lane];
    for (int i = 0; i < c; ++i)
        v = fmaxf(v, scratch[(qs + i) * 64 + lane]);
    out[(n >> 10) * 65536 + lane * 1024 + (n & 1023)] = v;
}

extern "C" void kernel_launch(void* const* d_in, const int* in_sizes, int n_in,
                              void* d_out, int out_size, void* d_ws, size_t ws_size,
                              hipStream_t stream) {
    const float* x     = (const float*)d_in[0];
    const float* pos   = (const float*)d_in[1];
    // d_in[2] = batch (unused: points are sorted, b = idx >> 10)
    const float* W1    = (const float*)d_in[3];
    const float* b1    = (const float*)d_in[4];
    const float* gamma = (const float*)d_in[5];
    const float* beta  = (const float*)d_in[6];
    const float* W2    = (const float*)d_in[7];
    const float* b2    = (const float*)d_in[8];
    float* out = (float*)d_out;
    char* ws = (char*)d_ws;
    int*   nbrs     = (int*)(ws + WS_NBRS);
    int*   nbr_cnt  = (int*)(ws + WS_NBRCNT);
    float* scsh     = (float*)(ws + WS_SCSH);
    unsigned short* w2b = (unsigned short*)(ws + WS_W2B);
    unsigned short* w2b32 = (unsigned short*)(ws + WS_W2B32);
    float* partials = (float*)(ws + WS_PART);
    unsigned int* yb = (unsigned int*)(ws + WS_Y);
    float* scratch  = (float*)(ws + WS_SCRATCH);        // overlays yb (dead after k_self)
    unsigned int* wbuf = (unsigned int*)(ws + WS_WB);
    int* qcnt   = (int*)(ws + WS_QCNT);
    int* qstart = (int*)(ws + WS_QSTART);
    int* qlist  = (int*)(ws + WS_QLIST);
    int* islot  = (int*)(ws + WS_ISLOT);
    float* selfbuf = (float*)(ws + WS_SELF);
    unsigned int* shpbuf = (unsigned int*)(ws + WS_SHP);
    float* bqpart   = (float*)(ws + WS_BQPART);         // overlays self+shp (dead before k_self)

    k_bq<<<1056, 256, 0, stream>>>(pos, nbrs, nbr_cnt, bqpart, W2, w2b, w2b32,
                                   qcnt, qstart, qlist, islot);
    k_y<<<256, 512, 0, stream>>>(x, W1, b1, pos, bqpart, yb, partials);
    k_finalize<<<1, 256, 0, stream>>>(gamma, beta, W1, partials, bqpart, scsh);
    k_self<<<NPTS / 64, 256, 0, stream>>>(yb, pos, W1, scsh, w2b, b2, qcnt,
                                          wbuf, shpbuf, selfbuf, out);
    k_out<<<NPTS / 16, 256, 0, stream>>>(wbuf, shpbuf, pos, w2b32, b2,
                                         nbrs, nbr_cnt, islot, scratch);
    k_gather<<<NPTS / 4, 256, 0, stream>>>(scratch, selfbuf, qcnt, qstart, out);
}